// Round 11
// baseline (263.012 us; speedup 1.0000x reference)
//
#include <hip/hip_runtime.h>
#include <cstdint>

typedef __bf16 bf16x8 __attribute__((ext_vector_type(8)));
typedef float f32x16 __attribute__((ext_vector_type(16)));

__device__ __forceinline__ unsigned short f2b(float f) {
    union { float f; uint32_t u; } x; x.f = f;
    uint32_t r = (x.u + 0x7fffu + ((x.u >> 16) & 1u)) >> 16;
    return (unsigned short)r;
}
__device__ __forceinline__ float b2f(unsigned short h) {
    union { float f; uint32_t u; } x; x.u = ((uint32_t)h) << 16;
    return x.f;
}

// ------- fused prep: x fp32->bf16 (blocks 0..8191) + W transpose->bf16 (8192..11263)
//         + rowsum zeroing (block 11264) -------
__global__ __launch_bounds__(256) void prep_kernel(const float* __restrict__ x,
                                                   unsigned short* __restrict__ xb,
                                                   const float* __restrict__ Wq,
                                                   const float* __restrict__ Wk,
                                                   const float* __restrict__ Wv,
                                                   unsigned short* __restrict__ Wt,
                                                   float* __restrict__ rowsum) {
    const int bid = blockIdx.x;
    const int tid = threadIdx.x;
    if (bid < 8192) {
        int i = (bid * 256 + tid) * 4;
        float4 v = *(const float4*)(x + i);
        ushort4 o;
        o.x = f2b(v.x); o.y = f2b(v.y); o.z = f2b(v.z); o.w = f2b(v.w);
        *(ushort4*)(xb + i) = o;
    } else if (bid < 11264) {
        __shared__ float tile[32][33];
        const int b = bid - 8192;          // 0..3071
        const int z = b >> 10;             // which W
        const int rem = b & 1023;
        const int n0 = (rem & 31) * 32;
        const int k0 = (rem >> 5) * 32;
        const float* W = (z == 0) ? Wq : (z == 1) ? Wk : Wv;
        const int tx = tid & 31, ty4 = tid >> 5;   // 0..7
#pragma unroll
        for (int i = 0; i < 4; ++i)
            tile[ty4 * 4 + i][tx] = W[(k0 + ty4 * 4 + i) * 1024 + n0 + tx];
        __syncthreads();
#pragma unroll
        for (int i = 0; i < 4; ++i) {
            const int row = ty4 * 4 + i;   // n within tile
            Wt[((long)z * 1024 + n0 + row) * 1024 + k0 + tx] = f2b(tile[tx][row]);
        }
    } else {
        // zero the 8192-float rowsum accumulator (re-zeroed every graph replay,
        // stream-ordered before the scores dispatch's atomics)
#pragma unroll
        for (int i = 0; i < 32; ++i) rowsum[i * 256 + tid] = 0.0f;
    }
}

// ---------------- BT-form bf16 MFMA GEMM: C[m][n] = sum_k A[m][k]*B[n][k] ----------------
// 128x128 block tile, BK=64, 256 threads (4 waves, 2x2 of 32x32 wave-tiles via
// v_mfma_f32_32x32x16_bf16). LDS rows hold 64 bf16 with an XOR-swizzle on 16B chunks,
// applied at staging time via the global source address (global_load_lds dest lane-linear).
// K-loop double-buffered, ONE barrier per K-step (prefetch issued BEFORE compute).
// Verified plateau on this problem: ~720-740 TF (r7/r8).
//
// XCD-aware bijective block swizzle (T1, m204) is applied ONLY for EPI 1/2 (scores, PV):
// r8 measured their FETCH at 139 MB vs 48 MB unique (panel re-reads missing L2); r10
// measured the swizzle recovering ~12 us combined there. For EPI 0 (QKV) the swizzle
// HURT (70.3 -> 73.0 us, FETCH 77 -> 84 MB): Wt (6 MB) is cache-resident everywhere and
// default x-major order already shares x-panels; remapping broke that. So QKV keeps the
// identity mapping. [measured r9 vs r10 within-problem A/B]
//
// EPI 0: QKV projection epilogue (bias, Q scale 1/32, V transposed store)
// EPI 1: scores epilogue — writes exp(logit) bf16 to S (ldc=2048) UNNORMALIZED
//        (|logit| <~ 2.5 by construction) and accumulates per-row sums into rowsum
//        via shuffle-reduce + one atomicAdd per row per block.
// EPI 2: PV epilogue — fp32 store scaled by 1/rowsum[row] (completes the softmax).
template <int EPI>
__global__ __launch_bounds__(256) void gemm32(const unsigned short* __restrict__ A, int lda, long sA,
                                              const unsigned short* __restrict__ Bm, int ldb, long sB,
                                              void* __restrict__ Cv, long sC, int K,
                                              const float* __restrict__ bq, const float* __restrict__ bk,
                                              const float* __restrict__ bv,
                                              unsigned short* __restrict__ Qb,
                                              unsigned short* __restrict__ Kb,
                                              unsigned short* __restrict__ Vt,
                                              float* __restrict__ rowsum) {
    __shared__ unsigned short As0[128 * 64];
    __shared__ unsigned short Bs0[128 * 64];
    __shared__ unsigned short As1[128 * 64];
    __shared__ unsigned short Bs1[128 * 64];

    // ---- block index mapping: identity for QKV, XCD-bijective swizzle for scores/PV ----
    int bxi, byi, bzi;
    if constexpr (EPI == 0) {
        bxi = blockIdx.x; byi = blockIdx.y; bzi = blockIdx.z;
    } else {
        const int gx = gridDim.x, gy = gridDim.y;
        const int total = gx * gy * gridDim.z;
        int lin = (blockIdx.z * gy + blockIdx.y) * gx + blockIdx.x;
        lin = (lin & 7) * (total >> 3) + (lin >> 3);
        bxi = lin % gx;
        byi = (lin / gx) % gy;
        bzi = lin / (gx * gy);
    }

    const int tid = threadIdx.x;
    const int wave = tid >> 6, lane = tid & 63;
    const int h = lane >> 5;
    const int l31 = lane & 31;
    const int wm = wave >> 1, wn = wave & 1;
    const long bm = (long)byi * 128;
    const long bn = (long)bxi * 128;

    const unsigned short* Ab = A + (long)bzi * sA;
    const unsigned short* Bb = Bm + (long)bzi * sB;

    f32x16 acc[2][2];
#pragma unroll
    for (int mi = 0; mi < 2; ++mi) {
#pragma unroll
        for (int ni = 0; ni < 2; ++ni) {
#pragma unroll
            for (int r = 0; r < 16; ++r) acc[mi][ni][r] = 0.0f;
        }
    }

    const int srow_in = lane >> 3;
    const int cswz = (lane & 7) ^ srow_in;
    const unsigned short* aptr[4];
    const unsigned short* bptr[4];
    int sloff[4];
#pragma unroll
    for (int j = 0; j < 4; ++j) {
        const int row = j * 32 + wave * 8 + srow_in;
        aptr[j] = Ab + (bm + row) * (long)lda + cswz * 8;
        bptr[j] = Bb + (bn + row) * (long)ldb + cswz * 8;
        sloff[j] = (j * 32 + wave * 8) * 64;
    }

    const int arow0 = (wm * 64 + l31) * 64;
    const int brow0 = (wn * 64 + l31) * 64;
    int sw[4];
#pragma unroll
    for (int kh = 0; kh < 4; ++kh)
        sw[kh] = (((2 * kh + h) ^ (lane & 7)) * 8);

#define STAGE(AsB, BsB, kofs)                                                                           \
    do {                                                                                                \
        _Pragma("unroll")                                                                               \
        for (int j = 0; j < 4; ++j) {                                                                   \
            __builtin_amdgcn_global_load_lds(                                                           \
                (const __attribute__((address_space(1))) void*)(aptr[j] + (kofs)),                      \
                (__attribute__((address_space(3))) void*)(&AsB[sloff[j]]), 16, 0, 0);                   \
            __builtin_amdgcn_global_load_lds(                                                           \
                (const __attribute__((address_space(1))) void*)(bptr[j] + (kofs)),                      \
                (__attribute__((address_space(3))) void*)(&BsB[sloff[j]]), 16, 0, 0);                   \
        }                                                                                               \
    } while (0)

#define COMPUTE_T(AsB, BsB)                                                                             \
    do {                                                                                                \
        _Pragma("unroll")                                                                               \
        for (int kp = 0; kp < 2; ++kp) {                                                                \
            bf16x8 af[2][2], bfr[2][2];                                                                 \
            _Pragma("unroll")                                                                           \
            for (int mi = 0; mi < 2; ++mi) {                                                            \
                _Pragma("unroll")                                                                       \
                for (int kk = 0; kk < 2; ++kk) {                                                        \
                    af[mi][kk] = *(const bf16x8*)&AsB[arow0 + mi * 32 * 64 + sw[kp * 2 + kk]];          \
                }                                                                                       \
            }                                                                                           \
            _Pragma("unroll")                                                                           \
            for (int ni = 0; ni < 2; ++ni) {                                                            \
                _Pragma("unroll")                                                                       \
                for (int kk = 0; kk < 2; ++kk) {                                                        \
                    bfr[ni][kk] = *(const bf16x8*)&BsB[brow0 + ni * 32 * 64 + sw[kp * 2 + kk]];         \
                }                                                                                       \
            }                                                                                           \
            _Pragma("unroll")                                                                           \
            for (int kk = 0; kk < 2; ++kk) {                                                            \
                _Pragma("unroll")                                                                       \
                for (int mi = 0; mi < 2; ++mi) {                                                        \
                    _Pragma("unroll")                                                                   \
                    for (int ni = 0; ni < 2; ++ni) {                                                    \
                        acc[mi][ni] = __builtin_amdgcn_mfma_f32_32x32x16_bf16(af[mi][kk], bfr[ni][kk],  \
                                                                              acc[mi][ni], 0, 0, 0);    \
                    }                                                                                   \
                }                                                                                       \
            }                                                                                           \
        }                                                                                               \
    } while (0)

    STAGE(As0, Bs0, 0);

    for (int k0 = 0; k0 < K; k0 += 128) {
        __syncthreads();
        STAGE(As1, Bs1, k0 + 64);
        COMPUTE_T(As0, Bs0);
        __syncthreads();
        if (k0 + 128 < K) STAGE(As0, Bs0, k0 + 128);
        COMPUTE_T(As1, Bs1);
    }

#undef STAGE
#undef COMPUTE_T

    // ---- epilogues. 32x32 C/D layout: col = lane&31, row = (reg&3) + 8*(reg>>2) + 4*(lane>>5)
    if constexpr (EPI == 0) {
#pragma unroll
        for (int mi = 0; mi < 2; ++mi) {
#pragma unroll
            for (int ni = 0; ni < 2; ++ni) {
                const f32x16 a = acc[mi][ni];
                const long col = bn + wn * 64 + ni * 32 + l31;
                const long rowB = bm + wm * 64 + mi * 32 + h * 4;
                if (col < 1024) {
                    const float bias = bq[col];
#pragma unroll
                    for (int g = 0; g < 4; ++g) {
#pragma unroll
                        for (int r = 0; r < 4; ++r)
                            Qb[(rowB + g * 8 + r) * 1024 + col] = f2b((a[g * 4 + r] + bias) * 0.03125f);
                    }
                } else if (col < 2048) {
                    const float bias = bk[col - 1024];
#pragma unroll
                    for (int g = 0; g < 4; ++g) {
#pragma unroll
                        for (int r = 0; r < 4; ++r)
                            Kb[(rowB + g * 8 + r) * 1024 + (col - 1024)] = f2b(a[g * 4 + r] + bias);
                    }
                } else {
                    const float bias = bv[col - 2048];
#pragma unroll
                    for (int g = 0; g < 4; ++g) {
                        const long row0 = rowB + g * 8;
                        const long batch = row0 >> 11;
                        const int n = (int)(row0 & 2047);
                        ushort4 o;
                        o.x = f2b(a[g * 4 + 0] + bias);
                        o.y = f2b(a[g * 4 + 1] + bias);
                        o.z = f2b(a[g * 4 + 2] + bias);
                        o.w = f2b(a[g * 4 + 3] + bias);
                        *(ushort4*)&Vt[(batch * 1024 + (col - 2048)) * 2048 + n] = o;
                    }
                }
            }
        }
    } else if constexpr (EPI == 1) {
        // unnormalized exp + per-row sum accumulation
        unsigned short* S = (unsigned short*)Cv + (long)bzi * sC;
        float* rs = rowsum + (long)bzi * 2048;
        const long c0 = bn + wn * 64 + l31;
#pragma unroll
        for (int mi = 0; mi < 2; ++mi) {
            const long rB = bm + wm * 64 + mi * 32 + h * 4;
#pragma unroll
            for (int g = 0; g < 4; ++g) {
#pragma unroll
                for (int r = 0; r < 4; ++r) {
                    const long row = rB + g * 8 + r;
                    const float e0 = __expf(acc[mi][0][g * 4 + r]);
                    const float e1 = __expf(acc[mi][1][g * 4 + r]);
                    S[row * 2048 + c0] = f2b(e0);
                    S[row * 2048 + c0 + 32] = f2b(e1);
                    float es = e0 + e1;
#pragma unroll
                    for (int off = 16; off; off >>= 1) es += __shfl_xor(es, off, 64);
                    if (l31 == 0) atomicAdd(&rs[row], es);
                }
            }
        }
    } else {
        // PV: scale by 1/rowsum[row] to complete the softmax
        float* O = (float*)Cv + (long)bzi * sC;
        const float* rs = rowsum + (long)bzi * 2048;
#pragma unroll
        for (int mi = 0; mi < 2; ++mi) {
            const long rB = bm + wm * 64 + mi * 32 + h * 4;
#pragma unroll
            for (int g = 0; g < 4; ++g) {
#pragma unroll
                for (int r = 0; r < 4; ++r) {
                    const long row = rB + g * 8 + r;
                    const float inv = 1.0f / rs[row];
#pragma unroll
                    for (int ni = 0; ni < 2; ++ni) {
                        const long col = bn + wn * 64 + ni * 32 + l31;
                        O[row * 1024 + col] = acc[mi][ni][g * 4 + r] * inv;
                    }
                }
            }
        }
    }
}

extern "C" void kernel_launch(void* const* d_in, const int* in_sizes, int n_in,
                              void* d_out, int out_size, void* d_ws, size_t ws_size,
                              hipStream_t stream) {
    const float* x  = (const float*)d_in[0];
    const float* Wq = (const float*)d_in[1];
    const float* Wk = (const float*)d_in[2];
    const float* Wv = (const float*)d_in[3];
    const float* bq = (const float*)d_in[4];
    const float* bk = (const float*)d_in[5];
    const float* bv = (const float*)d_in[6];
    float* out = (float*)d_out;

    char* ws = (char*)d_ws;
    unsigned short* xb = (unsigned short*)ws; ws += 8192L * 1024 * 2;
    unsigned short* Wt = (unsigned short*)ws; ws += 3072L * 1024 * 2;
    unsigned short* Qb = (unsigned short*)ws; ws += 8192L * 1024 * 2;
    unsigned short* Kb = (unsigned short*)ws; ws += 8192L * 1024 * 2;
    unsigned short* Vt = (unsigned short*)ws; ws += 4L * 1024 * 2048 * 2;
    unsigned short* S  = (unsigned short*)ws; ws += 4L * 2048 * 2048 * 2;
    float* rowsum      = (float*)ws;          ws += 8192L * 4;

    // 1. fused: x -> bf16  +  W -> Wt (bf16, transposed)  +  rowsum zeroing
    prep_kernel<<<8192 + 3072 + 1, 256, 0, stream>>>(x, xb, Wq, Wk, Wv, Wt, rowsum);
    // 2. QKV projection: [8192,3072] = xb @ Wt^T (+bias, Q scaled, V stored transposed)
    gemm32<0><<<dim3(24, 64, 1), 256, 0, stream>>>(xb, 1024, 0, Wt, 1024, 0,
                                                   nullptr, 0, 1024, bq, bk, bv, Qb, Kb, Vt, nullptr);
    // 3. scores + exp + rowsum: S[b] = exp(Q[b] @ K[b]^T) (Q pre-scaled by 1/32), rowsum += row sums
    gemm32<1><<<dim3(16, 16, 4), 256, 0, stream>>>(Qb, 1024, 2048L * 1024, Kb, 1024, 2048L * 1024,
                                                   S, 2048L * 2048, 1024,
                                                   nullptr, nullptr, nullptr, nullptr, nullptr, nullptr,
                                                   rowsum);
    // 4. out[b] = (expS[b] @ Vt[b]^T) / rowsum  (fp32 out, softmax completed in epilogue)
    gemm32<2><<<dim3(8, 16, 4), 256, 0, stream>>>(S, 2048, 2048L * 2048, Vt, 2048, 2048L * 1024,
                                                  out, 2048L * 1024, 2048,
                                                  nullptr, nullptr, nullptr, nullptr, nullptr, nullptr,
                                                  rowsum);
}